// Round 7
// baseline (212.122 us; speedup 1.0000x reference)
//
#include <hip/hip_runtime.h>
#include <math.h>

// ---------------------------------------------------------------------------
// TitansMemoryModule fused update, MI355X (gfx950) — round 7
//   K1: f32->bf16 convert of K,W + colk partials (proven)
//   K2: BARRIER-FREE GEMM: W col-strip (32x512, 32KB) resident in LDS
//       (loaded once, XOR-octet swizzle, one barrier total); A-fragments
//       per-lane direct from global k16; zero syncs in K-loop.
//       Fused epilogue: V read, diff16, loss/colv partials.
//   K3: grad = diff^T @ k (round-2 verbatim: split-K 32, XCD-grouped)
//   c1a/c1b: reductions + gates; c2-c4: momentum/weight + norm clips
// Output (flat f32): retrieved[16777216], loss, new_weight[262144],
//   new_momentum[262144], alpha, eta, theta
// ---------------------------------------------------------------------------

typedef __bf16 bf16x8 __attribute__((ext_vector_type(8)));
typedef float f32x4 __attribute__((ext_vector_type(4)));
typedef float float4_t __attribute__((ext_vector_type(4)));
typedef unsigned short ushort4_t __attribute__((ext_vector_type(4)));
typedef unsigned short ushort8_t __attribute__((ext_vector_type(8)));

#define OUT_LOSS   16777216
#define OUT_W      16777217
#define OUT_MOM    17039361
#define OUT_ALPHA  17301505

// ws layout (bytes), total 69,742,656 (round-6 layout kept)
#define OFF_GRAD   0u           // grad accum [512][512] f32 = 1 MB [memset 0]
#define OFF_CKP    1048576u     // colk_part [256][512] f32 (K1)
#define OFF_CVP    1572864u     // colv_part [128][512] f32 = 256 KB (K2)
#define OFF_LOSSP  2097152u     // loss_part [2048] f32 (K2)
#define OFF_COLK   2105344u     // colk [512] f32
#define OFF_COLV   2107392u     // colv [512] f32
#define OFF_SCAL   2109440u     // scal[16]: 1=||m||^2 2=||w||^2 3=a 4=e 5=t
#define OFF_W16    2109504u     // 512 KB bf16 W
#define OFF_K16    2633792u     // 32 MB bf16 K (row-major)
#define OFF_DIFF   36188224u    // 32 MB bf16 diff (row-major)
#define OFF_MRAW   OFF_K16      // m_raw aliases k16 (dead after K3)
#define OFF_WRAW   (OFF_K16 + 1048576u)

__device__ __forceinline__ ushort4_t cvt4(float4_t v) {
  union { __bf16 b; unsigned short u; } c0, c1, c2, c3;
  c0.b = (__bf16)v.x; c1.b = (__bf16)v.y; c2.b = (__bf16)v.z; c3.b = (__bf16)v.w;
  ushort4_t h; h.x = c0.u; h.y = c1.u; h.z = c2.u; h.w = c3.u;
  return h;
}

// ---------------------------------------------------------------------------
// K1: convert K (bid<256, 128 rows each) and W (bid 256..271, 32 rows each)
// to bf16; per-block column-sum partials for K (no atomics). Proven.
// ---------------------------------------------------------------------------
__global__ __launch_bounds__(256) void k1_convert(
    const float* __restrict__ Kp, const float* __restrict__ Wp,
    unsigned short* __restrict__ k16, unsigned short* __restrict__ w16,
    float* __restrict__ colk_part)
{
  __shared__ float cp[512];
  const int t = threadIdx.x;
  const int cg = t & 127;
  const int g = t >> 7;
  const int b = blockIdx.x;
  if (b < 256) {
    const int r0 = b << 7;
    float p0 = 0.f, p1 = 0.f, p2 = 0.f, p3 = 0.f;
#pragma unroll 4
    for (int rr = g; rr < 128; rr += 2) {
      const size_t off = (size_t)(r0 + rr) * 512 + (cg << 2);
      const float4_t v = *reinterpret_cast<const float4_t*>(&Kp[off]);
      *reinterpret_cast<ushort4_t*>(&k16[off]) = cvt4(v);
      p0 += v.x; p1 += v.y; p2 += v.z; p3 += v.w;
    }
    if (g == 1) {
      cp[(cg << 2) + 0] = p0; cp[(cg << 2) + 1] = p1;
      cp[(cg << 2) + 2] = p2; cp[(cg << 2) + 3] = p3;
    }
    __syncthreads();
    if (g == 0) {
      colk_part[(size_t)b * 512 + (cg << 2) + 0] = p0 + cp[(cg << 2) + 0];
      colk_part[(size_t)b * 512 + (cg << 2) + 1] = p1 + cp[(cg << 2) + 1];
      colk_part[(size_t)b * 512 + (cg << 2) + 2] = p2 + cp[(cg << 2) + 2];
      colk_part[(size_t)b * 512 + (cg << 2) + 3] = p3 + cp[(cg << 2) + 3];
    }
  } else {
    const int r0 = (b - 256) << 5;
#pragma unroll 4
    for (int rr = g; rr < 32; rr += 2) {
      const size_t off = (size_t)(r0 + rr) * 512 + (cg << 2);
      const float4_t v = *reinterpret_cast<const float4_t*>(&Wp[off]);
      *reinterpret_cast<ushort4_t*>(&w16[off]) = cvt4(v);
    }
  }
}

// ---------------------------------------------------------------------------
// K2: retrieved = k16 @ w16^T, barrier-free.
// Block: 256 rows x 32 cols; 4 waves, wave wv = rows wv*64..+64, all 32 cols.
// W strip [32 c][512 k] staged once into LDS, octet-swizzled (slot o^(c&7));
// ONE barrier, then K-loop: A per-lane from global, B ds_read_b128 swizzled,
// 8 MFMA per K=32 step, no syncs. Grid 2048, XCD-grouped (16 rt x 16 vt
// per XCD -> 4MB k16 slab L2-resident, re-read by 16 col-strips).
// ---------------------------------------------------------------------------
__global__ __launch_bounds__(256, 4) void k2_gemm(
    const unsigned short* __restrict__ k16, const unsigned short* __restrict__ w16,
    const float* __restrict__ Vp, float* __restrict__ outp,
    unsigned short* __restrict__ diff16,
    float* __restrict__ colv_part, float* __restrict__ loss_part)
{
  __shared__ __align__(16) unsigned short Bs[32 * 512];   // 32 KB, swizzled
  __shared__ float redc[128];
  __shared__ float redl[4];

  const int t = threadIdx.x, lane = t & 63, wv = t >> 6;
  const int tile = (blockIdx.x & 7) * 256 + (blockIdx.x >> 3);  // XCD-grouped
  const int rt = tile >> 4, vt = tile & 15;
  const int row0 = rt << 8, vd0 = vt << 5;

  // --- stage W strip once: thread t -> col c = t>>3, octet-phase p = t&7
  {
    const int c = t >> 3, p = t & 7;
    const unsigned short* src = w16 + (size_t)(vd0 + c) * 512;
#pragma unroll
    for (int e = 0; e < 8; ++e) {
      const int o = p + (e << 3);              // octet 0..63
      const ushort8_t v = *reinterpret_cast<const ushort8_t*>(&src[o << 3]);
      *reinterpret_cast<ushort8_t*>(&Bs[(c << 9) + ((o ^ (c & 7)) << 3)]) = v;
    }
  }
  __syncthreads();   // the only barrier

  f32x4 acc[4][2];
#pragma unroll
  for (int m = 0; m < 4; ++m)
#pragma unroll
    for (int n = 0; n < 2; ++n)
      acc[m][n] = (f32x4){0.f, 0.f, 0.f, 0.f};

  const int fr = lane & 15, fq = lane >> 4;
  // A base: row = row0 + wv*64 + m*16 + fr ; k = kb*32 + fq*8
  const unsigned short* pA = k16 + (size_t)(row0 + (wv << 6) + fr) * 512 + (fq << 3);

#pragma unroll 4
  for (int kb = 0; kb < 16; ++kb) {
    bf16x8 af[4], bfv[2];
#pragma unroll
    for (int m = 0; m < 4; ++m)
      af[m] = *reinterpret_cast<const bf16x8*>(&pA[(m << 13) + (kb << 5)]);
#pragma unroll
    for (int n = 0; n < 2; ++n) {
      const int c = (n << 4) + fr;
      const int s = ((kb << 2) + fq) ^ (c & 7);
      bfv[n] = *reinterpret_cast<const bf16x8*>(&Bs[(c << 9) + (s << 3)]);
    }
#pragma unroll
    for (int m = 0; m < 4; ++m)
#pragma unroll
      for (int n = 0; n < 2; ++n)
        acc[m][n] = __builtin_amdgcn_mfma_f32_16x16x32_bf16(af[m], bfv[n], acc[m][n], 0, 0, 0);
  }

  // epilogue: retrieved + diff16 + loss/colv partials (plain stores only)
  float lsum = 0.f;
  float vcs[2] = {0.f, 0.f};
#pragma unroll
  for (int m = 0; m < 4; ++m) {
#pragma unroll
    for (int n = 0; n < 2; ++n) {
#pragma unroll
      for (int i = 0; i < 4; ++i) {
        const int rl = (wv << 6) + (m << 4) + (fq << 2) + i;   // 0..255
        const int cl = (n << 4) + fr;                          // 0..31
        const size_t oi = (size_t)(row0 + rl) * 512 + vd0 + cl;
        const float rv = acc[m][n][i];
        outp[oi] = rv;
        const float vv = Vp[oi];
        const float d = rv - vv;
        lsum += d * d;
        vcs[n] += vv;
        union { __bf16 b; unsigned short u; } cd; cd.b = (__bf16)d;
        diff16[oi] = cd.u;
      }
    }
  }
#pragma unroll
  for (int o = 32; o; o >>= 1) lsum += __shfl_xor(lsum, o);
  if (lane == 0) redl[wv] = lsum;
#pragma unroll
  for (int n = 0; n < 2; ++n) {
    vcs[n] += __shfl_xor(vcs[n], 16);
    vcs[n] += __shfl_xor(vcs[n], 32);
  }
  if (fq == 0) {
#pragma unroll
    for (int n = 0; n < 2; ++n)
      redc[(wv << 5) + (n << 4) + fr] = vcs[n];
  }
  __syncthreads();
  if (t < 32) {   // column t of this block's 32-col slab, sum 4 waves
    colv_part[(size_t)rt * 512 + vd0 + t] =
        redc[t] + redc[32 + t] + redc[64 + t] + redc[96 + t];
  }
  if (t == 0)
    loss_part[tile] = redl[0] + redl[1] + redl[2] + redl[3];
}

// ---------------------------------------------------------------------------
// K3: grad += diff^T @ k  (round-2 verbatim: split-K 32 chunks of 1024 rows,
// XCD-grouped, transposed LDS staging, f32 atomics).
// ---------------------------------------------------------------------------
__global__ __launch_bounds__(256) void k3_grad(
    const unsigned short* __restrict__ diff16,
    const unsigned short* __restrict__ k16,
    float* __restrict__ grad)
{
  __shared__ __align__(16) unsigned short At[2][128][40];
  __shared__ __align__(16) unsigned short Bt[2][128][40];
  const int t = threadIdx.x;
  const int lane = t & 63;
  const int wv = t >> 6;
  const int b = blockIdx.x;
  const int x = b & 7;
  const int q = b >> 3;
  const int tile = q & 15;
  const int kc = ((q >> 4) << 3) | x;
  const int vd0 = (tile & 3) << 7;
  const int kd0 = (tile >> 2) << 7;
  const size_t r0 = (size_t)kc << 10;

  f32x4 acc[4][4];
#pragma unroll
  for (int m = 0; m < 4; ++m)
#pragma unroll
    for (int n = 0; n < 4; ++n)
      acc[m][n] = (f32x4){0.f, 0.f, 0.f, 0.f};

  const int dr = t >> 3;
  const int c0 = (t & 7) << 4;
  const int wr = (wv >> 1) << 6;
  const int wc = (wv & 1) << 6;
  const int fr = lane & 15;
  const int fq = lane >> 4;

  int cur = 0;
  for (int rr = 0; rr < 1024; rr += 32) {
    const size_t rowoff = (r0 + rr + dr) << 9;
    const ushort8_t a0 = *reinterpret_cast<const ushort8_t*>(&diff16[rowoff + vd0 + c0]);
    const ushort8_t a1 = *reinterpret_cast<const ushort8_t*>(&diff16[rowoff + vd0 + c0 + 8]);
    const ushort8_t b0 = *reinterpret_cast<const ushort8_t*>(&k16[rowoff + kd0 + c0]);
    const ushort8_t b1 = *reinterpret_cast<const ushort8_t*>(&k16[rowoff + kd0 + c0 + 8]);
    const int swz = ((c0 >> 4) & 3) << 3;
#pragma unroll
    for (int j = 0; j < 8; ++j) {
      const int drs = dr ^ swz;
      At[cur][c0 + j][drs] = a0[j];
      At[cur][c0 + 8 + j][drs] = a1[j];
      Bt[cur][c0 + j][drs] = b0[j];
      Bt[cur][c0 + 8 + j][drs] = b1[j];
    }
    __syncthreads();
    bf16x8 af[4], bfv[4];
#pragma unroll
    for (int m = 0; m < 4; ++m) {
      const int rA = wr + (m << 4) + fr;
      af[m] = *reinterpret_cast<const bf16x8*>(&At[cur][rA][(fq ^ ((rA >> 4) & 3)) << 3]);
    }
#pragma unroll
    for (int n = 0; n < 4; ++n) {
      const int rB = wc + (n << 4) + fr;
      bfv[n] = *reinterpret_cast<const bf16x8*>(&Bt[cur][rB][(fq ^ ((rB >> 4) & 3)) << 3]);
    }
#pragma unroll
    for (int m = 0; m < 4; ++m)
#pragma unroll
      for (int n = 0; n < 4; ++n)
        acc[m][n] = __builtin_amdgcn_mfma_f32_16x16x32_bf16(af[m], bfv[n], acc[m][n], 0, 0, 0);
    cur ^= 1;
  }
#pragma unroll
  for (int m = 0; m < 4; ++m)
#pragma unroll
    for (int n = 0; n < 4; ++n)
#pragma unroll
      for (int i = 0; i < 4; ++i)
        atomicAdd(&grad[(size_t)(vd0 + wr + (m << 4) + (fq << 2) + i) * 512
                        + kd0 + wc + (n << 4) + fr], acc[m][n][i]);
}

// ---------------------------------------------------------------------------
// c1a: reduce colk partials (256) and colv partials (128) -> colk/colv[512]
// ---------------------------------------------------------------------------
__global__ __launch_bounds__(256) void c1a_redcols(
    const float* __restrict__ ckp, const float* __restrict__ cvp,
    float* __restrict__ colk, float* __restrict__ colv)
{
  __shared__ float red[8][32];
  const int t = threadIdx.x, b = blockIdx.x;
  const int mtx = b >> 4;
  const int c = ((b & 15) << 5) + (t & 31);
  const int pg = t >> 5;
  const float* src = mtx ? cvp : ckp;
  const int P = mtx ? 128 : 256;
  float s = 0.f;
  for (int p = pg; p < P; p += 8) s += src[(size_t)p * 512 + c];
  red[pg][t & 31] = s;
  __syncthreads();
  if (pg == 0) {
    float tot = 0.f;
#pragma unroll
    for (int j = 0; j < 8; ++j) tot += red[j][t & 31];
    (mtx ? colv : colk)[c] = tot;
  }
}

// ---------------------------------------------------------------------------
// c1b: gates + loss finalize (1 block); zeroes norm accumulators.
// ---------------------------------------------------------------------------
__global__ __launch_bounds__(256) void c1b_gates(
    const float* __restrict__ gw, const float* __restrict__ gb,
    const float* __restrict__ colk, const float* __restrict__ colv,
    const float* __restrict__ lossp, float* __restrict__ scal,
    float* __restrict__ outp)
{
  __shared__ float red3[3][4];
  __shared__ float redl[4];
  const int t = threadIdx.x, lane = t & 63, wvi = t >> 6;
  float p3[3] = {0.f, 0.f, 0.f};
  for (int j = t; j < 1024; j += 256) {
    const float kv = (j < 512 ? colk[j] : colv[j - 512]) * (1.0f / 32768.0f);
    p3[0] += kv * gw[j];
    p3[1] += kv * gw[1024 + j];
    p3[2] += kv * gw[2048 + j];
  }
  float ls = 0.f;
#pragma unroll
  for (int q = 0; q < 8; ++q) ls += lossp[t + (q << 8)];
#pragma unroll
  for (int o = 32; o; o >>= 1) {
    ls += __shfl_xor(ls, o);
#pragma unroll
    for (int g = 0; g < 3; ++g) p3[g] += __shfl_xor(p3[g], o);
  }
  if (lane == 0) {
    red3[0][wvi] = p3[0]; red3[1][wvi] = p3[1]; red3[2][wvi] = p3[2];
    redl[wvi] = ls;
  }
  __syncthreads();
  if (t == 0) {
    const float s0 = red3[0][0] + red3[0][1] + red3[0][2] + red3[0][3] + gb[0];
    const float s1 = red3[1][0] + red3[1][1] + red3[1][2] + red3[1][3] + gb[1];
    const float s2 = red3[2][0] + red3[2][1] + red3[2][2] + red3[2][3] + gb[2];
    const float alpha = 1.0f / (1.0f + expf(-s0));
    const float eta   = 1.0f / (1.0f + expf(-s1));
    const float theta = 1.0f / (1.0f + expf(-s2));
    scal[1] = 0.f; scal[2] = 0.f;
    scal[3] = alpha; scal[4] = eta; scal[5] = theta;
    outp[OUT_LOSS] = (redl[0] + redl[1] + redl[2] + redl[3]) * (1.0f / 16777216.0f);
    outp[OUT_ALPHA]     = alpha;
    outp[OUT_ALPHA + 1] = eta;
    outp[OUT_ALPHA + 2] = theta;
  }
}

__device__ __forceinline__ void block_atomic_sumsq(float sq, float* target) {
  __shared__ float red[4];
#pragma unroll
  for (int o = 32; o; o >>= 1) sq += __shfl_xor(sq, o);
  if ((threadIdx.x & 63) == 0) red[threadIdx.x >> 6] = sq;
  __syncthreads();
  if (threadIdx.x == 0) atomicAdd(target, red[0] + red[1] + red[2] + red[3]);
}

// c2: m_raw = eta*S - 0.005*theta*clip(grad); accumulate ||m||^2
__global__ __launch_bounds__(256) void c2_mom(
    const float* __restrict__ grad, const float* __restrict__ S,
    float* scal, float* __restrict__ m_raw)
{
  const float eta = scal[4];
  const float cth = 0.005f * scal[5];
  const int i = ((blockIdx.x << 8) + threadIdx.x) << 2;
  const float4_t g = *reinterpret_cast<const float4_t*>(&grad[i]);
  const float4_t s = *reinterpret_cast<const float4_t*>(&S[i]);
  float4_t m; float sq = 0.f;
#pragma unroll
  for (int j = 0; j < 4; ++j) {
    float gj = g[j] * (2.0f / 16777216.0f);
    gj = fminf(1.0f, fmaxf(-1.0f, gj));
    m[j] = eta * s[j] - cth * gj;
    sq += m[j] * m[j];
  }
  *reinterpret_cast<float4_t*>(&m_raw[i]) = m;
  block_atomic_sumsq(sq, &scal[1]);
}

// c3: clip momentum -> out; w_raw = (1-alpha)*W + m; accumulate ||w||^2
__global__ __launch_bounds__(256) void c3_wt(
    const float* __restrict__ m_raw, const float* __restrict__ memw,
    float* scal, float* __restrict__ w_raw, float* __restrict__ outp)
{
  const float nm = sqrtf(scal[1]);
  const float sm = nm > 5.0f ? 5.0f / (nm + 1e-8f) : 1.0f;
  const float oma = 1.0f - scal[3];
  const int i = ((blockIdx.x << 8) + threadIdx.x) << 2;
  const float4_t mr = *reinterpret_cast<const float4_t*>(&m_raw[i]);
  const float4_t wi = *reinterpret_cast<const float4_t*>(&memw[i]);
  float4_t w; float sq = 0.f;
#pragma unroll
  for (int j = 0; j < 4; ++j) {
    const float m = mr[j] * sm;
    outp[OUT_MOM + i + j] = m;
    w[j] = oma * wi[j] + m;
    sq += w[j] * w[j];
  }
  *reinterpret_cast<float4_t*>(&w_raw[i]) = w;
  block_atomic_sumsq(sq, &scal[2]);
}

// c4: clip weight -> out
__global__ __launch_bounds__(256) void c4_wt(
    const float* __restrict__ w_raw, const float* __restrict__ scal,
    float* __restrict__ outp)
{
  const float nw = sqrtf(scal[2]);
  const float sw = nw > 5.0f ? 5.0f / (nw + 1e-8f) : 1.0f;
  const int i = ((blockIdx.x << 8) + threadIdx.x) << 2;
  const float4_t w = *reinterpret_cast<const float4_t*>(&w_raw[i]);
#pragma unroll
  for (int j = 0; j < 4; ++j)
    outp[OUT_W + i + j] = w[j] * sw;
}

// ---------------------------------------------------------------------------
extern "C" void kernel_launch(void* const* d_in, const int* in_sizes, int n_in,
                              void* d_out, int out_size, void* d_ws, size_t ws_size,
                              hipStream_t stream)
{
  const float* Kp = (const float*)d_in[0];
  const float* Vp = (const float*)d_in[1];
  const float* Wp = (const float*)d_in[2];
  const float* GW = (const float*)d_in[3];
  const float* GB = (const float*)d_in[4];
  const float* Sp = (const float*)d_in[5];
  float* outp = (float*)d_out;
  char* ws = (char*)d_ws;

  float* grad            = (float*)(ws + OFF_GRAD);
  float* colk_part       = (float*)(ws + OFF_CKP);
  float* colv_part       = (float*)(ws + OFF_CVP);
  float* loss_part       = (float*)(ws + OFF_LOSSP);
  float* colk            = (float*)(ws + OFF_COLK);
  float* colv            = (float*)(ws + OFF_COLV);
  float* scal            = (float*)(ws + OFF_SCAL);
  unsigned short* w16    = (unsigned short*)(ws + OFF_W16);
  unsigned short* k16    = (unsigned short*)(ws + OFF_K16);
  unsigned short* diff16 = (unsigned short*)(ws + OFF_DIFF);
  float* m_raw           = (float*)(ws + OFF_MRAW);
  float* w_raw           = (float*)(ws + OFF_WRAW);

  hipMemsetAsync(ws + OFF_GRAD, 0, 1048576, stream);

  k1_convert<<<272, 256, 0, stream>>>(Kp, Wp, k16, w16, colk_part);
  k2_gemm<<<2048, 256, 0, stream>>>(k16, w16, Vp, outp, diff16, colv_part, loss_part);
  k3_grad<<<512, 256, 0, stream>>>(diff16, k16, grad);
  c1a_redcols<<<32, 256, 0, stream>>>(colk_part, colv_part, colk, colv);
  c1b_gates<<<1, 256, 0, stream>>>(GW, GB, colk, colv, loss_part, scal, outp);
  c2_mom<<<256, 256, 0, stream>>>(grad, Sp, scal, m_raw);
  c3_wt<<<256, 256, 0, stream>>>(m_raw, Wp, scal, w_raw, outp);
  c4_wt<<<256, 256, 0, stream>>>(w_raw, scal, outp);
}

// Round 8
// 167.878 us; speedup vs baseline: 1.2635x; 1.2635x over previous
//
#include <hip/hip_runtime.h>
#include <math.h>

// ---------------------------------------------------------------------------
// TitansMemoryModule fused update, MI355X (gfx950) — round 8
//   K1: f32->bf16 convert of K,W + colk partials + grad zeroing (no memset)
//   K2: round-2 verbatim GEMM (78us proven): 128x128, BK=64, single-buffer,
//       global_load_lds(16B), linear LDS. Loss via plain store.
//   K3: grad = diff^T @ k, round-2 layout verbatim + T14 async-STAGE split
//       (preload regs, write-late): load latency hides under MFMA+barrier.
//   c1a/c1b: reductions + gates; c2-c4: momentum/weight + norm clips
// Output (flat f32): retrieved[16777216], loss, new_weight[262144],
//   new_momentum[262144], alpha, eta, theta
// ---------------------------------------------------------------------------

typedef __bf16 bf16x8 __attribute__((ext_vector_type(8)));
typedef float f32x4 __attribute__((ext_vector_type(4)));
typedef float float4_t __attribute__((ext_vector_type(4)));
typedef unsigned short ushort4_t __attribute__((ext_vector_type(4)));
typedef unsigned short ushort8_t __attribute__((ext_vector_type(8)));

#define OUT_LOSS   16777216
#define OUT_W      16777217
#define OUT_MOM    17039361
#define OUT_ALPHA  17301505

// ws layout (bytes)
#define OFF_GRAD   0u           // grad accum [512][512] f32 = 1 MB [K1 zeroes]
#define OFF_CKP    1048576u     // colk_part [256][512] f32 = 512 KB (K1)
#define OFF_CVP    1572864u     // colv_part [256][512] f32 = 512 KB (K2)
#define OFF_LOSSP  2097152u     // loss_part [1024] f32 (plain stores, K2)
#define OFF_COLK   2105344u     // colk [512] f32
#define OFF_COLV   2107392u     // colv [512] f32
#define OFF_SCAL   2109440u     // scal[16]: 1=||m||^2 2=||w||^2 3=a 4=e 5=t
#define OFF_W16    2109504u     // 512 KB bf16 W
#define OFF_K16    2633792u     // 32 MB bf16 K (row-major)
#define OFF_DIFF   36188224u    // 32 MB bf16 diff (row-major)
#define OFF_MRAW   OFF_K16      // m_raw aliases k16 (dead after K3)
#define OFF_WRAW   (OFF_K16 + 1048576u)

__device__ __forceinline__ ushort4_t cvt4(float4_t v) {
  union { __bf16 b; unsigned short u; } c0, c1, c2, c3;
  c0.b = (__bf16)v.x; c1.b = (__bf16)v.y; c2.b = (__bf16)v.z; c3.b = (__bf16)v.w;
  ushort4_t h; h.x = c0.u; h.y = c1.u; h.z = c2.u; h.w = c3.u;
  return h;
}

__device__ __forceinline__ void gload_lds16(const unsigned short* g, unsigned short* l) {
  __builtin_amdgcn_global_load_lds(
      (const __attribute__((address_space(1))) unsigned int*)g,
      (__attribute__((address_space(3))) unsigned int*)l, 16, 0, 0);
}

// ---------------------------------------------------------------------------
// K1: blocks 0..255 convert K (128 rows each) + colk partials;
// 256..271 convert W (32 rows each); 272..287 zero grad (64 KB each).
// ---------------------------------------------------------------------------
__global__ __launch_bounds__(256) void k1_convert(
    const float* __restrict__ Kp, const float* __restrict__ Wp,
    unsigned short* __restrict__ k16, unsigned short* __restrict__ w16,
    float* __restrict__ colk_part, float* __restrict__ grad)
{
  __shared__ float cp[512];
  const int t = threadIdx.x;
  const int cg = t & 127;
  const int g = t >> 7;
  const int b = blockIdx.x;
  if (b < 256) {
    const int r0 = b << 7;
    float p0 = 0.f, p1 = 0.f, p2 = 0.f, p3 = 0.f;
#pragma unroll 4
    for (int rr = g; rr < 128; rr += 2) {
      const size_t off = (size_t)(r0 + rr) * 512 + (cg << 2);
      const float4_t v = *reinterpret_cast<const float4_t*>(&Kp[off]);
      *reinterpret_cast<ushort4_t*>(&k16[off]) = cvt4(v);
      p0 += v.x; p1 += v.y; p2 += v.z; p3 += v.w;
    }
    if (g == 1) {
      cp[(cg << 2) + 0] = p0; cp[(cg << 2) + 1] = p1;
      cp[(cg << 2) + 2] = p2; cp[(cg << 2) + 3] = p3;
    }
    __syncthreads();
    if (g == 0) {
      colk_part[(size_t)b * 512 + (cg << 2) + 0] = p0 + cp[(cg << 2) + 0];
      colk_part[(size_t)b * 512 + (cg << 2) + 1] = p1 + cp[(cg << 2) + 1];
      colk_part[(size_t)b * 512 + (cg << 2) + 2] = p2 + cp[(cg << 2) + 2];
      colk_part[(size_t)b * 512 + (cg << 2) + 3] = p3 + cp[(cg << 2) + 3];
    }
  } else if (b < 272) {
    const int r0 = (b - 256) << 5;
#pragma unroll 4
    for (int rr = g; rr < 32; rr += 2) {
      const size_t off = (size_t)(r0 + rr) * 512 + (cg << 2);
      const float4_t v = *reinterpret_cast<const float4_t*>(&Wp[off]);
      *reinterpret_cast<ushort4_t*>(&w16[off]) = cvt4(v);
    }
  } else {
    const int base = (b - 272) << 14;   // 16384 floats per block
    const float4_t z = (float4_t){0.f, 0.f, 0.f, 0.f};
#pragma unroll
    for (int j = 0; j < 16; ++j)
      *reinterpret_cast<float4_t*>(&grad[base + (j << 10) + (t << 2)]) = z;
  }
}

// ---------------------------------------------------------------------------
// K2: retrieved = k16 @ w16^T.  Round-2 verbatim (78us proven): 128x128 tile,
// BK=64, 4 waves (2x2 of 64x64), single-buffer, global_load_lds width 16,
// linear LDS [128][64]. XCD-grouped tile swizzle. Fused epilogue.
// Only delta vs round-2: loss_part[tile] plain store (no atomic, no memset).
// ---------------------------------------------------------------------------
__global__ __launch_bounds__(256) void k2_gemm(
    const unsigned short* __restrict__ k16, const unsigned short* __restrict__ w16,
    const float* __restrict__ Vp, float* __restrict__ outp,
    unsigned short* __restrict__ diff16,
    float* __restrict__ colv_part, float* __restrict__ loss_part)
{
  __shared__ __align__(16) unsigned short As[8192];   // [128][64] bf16, linear
  __shared__ __align__(16) unsigned short Bs[8192];
  __shared__ float redc[256];
  __shared__ float redl[4];

  const int t = threadIdx.x, lane = t & 63, wv = t >> 6;
  const int tile = (blockIdx.x & 7) * 128 + (blockIdx.x >> 3);
  const int rt = tile >> 2, vt = tile & 3;
  const int row0 = rt << 7, vd0 = vt << 7;

  f32x4 acc[4][4];
#pragma unroll
  for (int m = 0; m < 4; ++m)
#pragma unroll
    for (int n = 0; n < 4; ++n)
      acc[m][n] = (f32x4){0.f, 0.f, 0.f, 0.f};

  const int srow = (wv << 3) + (lane >> 3);
  const int scol = (lane & 7) << 3;
  const unsigned short* pA = k16 + (size_t)(row0 + srow) * 512 + scol;
  const unsigned short* pB = w16 + (size_t)(vd0 + srow) * 512 + scol;
  unsigned short* lA = &As[wv << 9];
  unsigned short* lB = &Bs[wv << 9];

  const int fr = lane & 15, fq = lane >> 4;
  const int wr = (wv >> 1) << 6, wc = (wv & 1) << 6;

  for (int kk0 = 0; kk0 < 512; kk0 += 64) {
#pragma unroll
    for (int i = 0; i < 4; ++i) {
      gload_lds16(pA + (i << 14) + kk0, lA + (i << 11));
      gload_lds16(pB + (i << 14) + kk0, lB + (i << 11));
    }
    __syncthreads();
#pragma unroll
    for (int kk = 0; kk < 64; kk += 32) {
      const int co = kk + (fq << 3);
      bf16x8 af[4], bfv[4];
#pragma unroll
      for (int m = 0; m < 4; ++m)
        af[m] = *reinterpret_cast<const bf16x8*>(&As[((wr + (m << 4) + fr) << 6) + co]);
#pragma unroll
      for (int n = 0; n < 4; ++n)
        bfv[n] = *reinterpret_cast<const bf16x8*>(&Bs[((wc + (n << 4) + fr) << 6) + co]);
#pragma unroll
      for (int m = 0; m < 4; ++m)
#pragma unroll
        for (int n = 0; n < 4; ++n)
          acc[m][n] = __builtin_amdgcn_mfma_f32_16x16x32_bf16(af[m], bfv[n], acc[m][n], 0, 0, 0);
    }
    __syncthreads();
  }

  float lsum = 0.f;
  float vcs[4] = {0.f, 0.f, 0.f, 0.f};
#pragma unroll
  for (int m = 0; m < 4; ++m) {
#pragma unroll
    for (int n = 0; n < 4; ++n) {
#pragma unroll
      for (int i = 0; i < 4; ++i) {
        const int gr = row0 + wr + (m << 4) + (fq << 2) + i;
        const int gc = vd0 + wc + (n << 4) + fr;
        const size_t oi = (size_t)gr * 512 + gc;
        const float rv = acc[m][n][i];
        outp[oi] = rv;
        const float vv = Vp[oi];
        const float d = rv - vv;
        lsum += d * d;
        vcs[n] += vv;
        union { __bf16 b; unsigned short u; } cd; cd.b = (__bf16)d;
        diff16[oi] = cd.u;
      }
    }
  }
#pragma unroll
  for (int o = 32; o; o >>= 1) lsum += __shfl_xor(lsum, o);
  if (lane == 0) redl[wv] = lsum;
#pragma unroll
  for (int n = 0; n < 4; ++n) {
    vcs[n] += __shfl_xor(vcs[n], 16);
    vcs[n] += __shfl_xor(vcs[n], 32);
  }
  if (fq == 0) {
#pragma unroll
    for (int n = 0; n < 4; ++n)
      redc[(wv << 6) + (n << 4) + fr] = vcs[n];
  }
  __syncthreads();
  if (t < 128) {
    const int side = t >> 6, lc = t & 63;
    colv_part[(size_t)rt * 512 + vd0 + t] =
        redc[side * 64 + lc] + redc[(side + 2) * 64 + lc];
  }
  if (t == 0)
    loss_part[tile] = redl[0] + redl[1] + redl[2] + redl[3];
}

// ---------------------------------------------------------------------------
// K3: grad += diff^T @ k. Round-2 layout/algebra verbatim; T14 async-STAGE:
// preload regs for step 0; per step {ds_write from cur regs -> issue next
// loads -> barrier -> MFMA -> swap}. 512 blocks, 32 chunks, XCD-grouped.
// ---------------------------------------------------------------------------
__global__ __launch_bounds__(256) void k3_grad(
    const unsigned short* __restrict__ diff16,
    const unsigned short* __restrict__ k16,
    float* __restrict__ grad)
{
  __shared__ __align__(16) unsigned short At[2][128][40];
  __shared__ __align__(16) unsigned short Bt[2][128][40];
  const int t = threadIdx.x;
  const int lane = t & 63;
  const int wv = t >> 6;
  const int b = blockIdx.x;
  const int x = b & 7;
  const int q = b >> 3;
  const int tile = q & 15;
  const int kc = ((q >> 4) << 3) | x;       // all 16 tiles of kc share an XCD
  const int vd0 = (tile & 3) << 7;
  const int kd0 = (tile >> 2) << 7;
  const size_t r0 = (size_t)kc << 10;

  f32x4 acc[4][4];
#pragma unroll
  for (int m = 0; m < 4; ++m)
#pragma unroll
    for (int n = 0; n < 4; ++n)
      acc[m][n] = (f32x4){0.f, 0.f, 0.f, 0.f};

  const int dr = t >> 3;
  const int c0 = (t & 7) << 4;
  const int wr = (wv >> 1) << 6;
  const int wc = (wv & 1) << 6;
  const int fr = lane & 15;
  const int fq = lane >> 4;
  const int swz = ((c0 >> 4) & 3) << 3;
  const int drs = dr ^ swz;

  // T14 preload: step-0 regs
  {
    const size_t ro = (r0 + dr) << 9;
    // fallthrough into loop vars below
  }
  ushort8_t ca0, ca1, cb0, cb1;
  {
    const size_t ro = (r0 + dr) << 9;
    ca0 = *reinterpret_cast<const ushort8_t*>(&diff16[ro + vd0 + c0]);
    ca1 = *reinterpret_cast<const ushort8_t*>(&diff16[ro + vd0 + c0 + 8]);
    cb0 = *reinterpret_cast<const ushort8_t*>(&k16[ro + kd0 + c0]);
    cb1 = *reinterpret_cast<const ushort8_t*>(&k16[ro + kd0 + c0 + 8]);
  }

  int cur = 0;
  for (int s = 0; s < 32; ++s) {
    // stage current regs (vmcnt wait lands here, one step after issue)
#pragma unroll
    for (int j = 0; j < 8; ++j) {
      At[cur][c0 + j][drs] = ca0[j];
      At[cur][c0 + 8 + j][drs] = ca1[j];
      Bt[cur][c0 + j][drs] = cb0[j];
      Bt[cur][c0 + 8 + j][drs] = cb1[j];
    }
    // issue next step's loads (latency hides under barrier + MFMA)
    const int rrn = (s < 31) ? ((s + 1) << 5) : 0;
    const size_t ron = (r0 + rrn + dr) << 9;
    const ushort8_t na0 = *reinterpret_cast<const ushort8_t*>(&diff16[ron + vd0 + c0]);
    const ushort8_t na1 = *reinterpret_cast<const ushort8_t*>(&diff16[ron + vd0 + c0 + 8]);
    const ushort8_t nb0 = *reinterpret_cast<const ushort8_t*>(&k16[ron + kd0 + c0]);
    const ushort8_t nb1 = *reinterpret_cast<const ushort8_t*>(&k16[ron + kd0 + c0 + 8]);
    __syncthreads();
    bf16x8 af[4], bfv[4];
#pragma unroll
    for (int m = 0; m < 4; ++m) {
      const int rA = wr + (m << 4) + fr;
      af[m] = *reinterpret_cast<const bf16x8*>(&At[cur][rA][(fq ^ ((rA >> 4) & 3)) << 3]);
    }
#pragma unroll
    for (int n = 0; n < 4; ++n) {
      const int rB = wc + (n << 4) + fr;
      bfv[n] = *reinterpret_cast<const bf16x8*>(&Bt[cur][rB][(fq ^ ((rB >> 4) & 3)) << 3]);
    }
#pragma unroll
    for (int m = 0; m < 4; ++m)
#pragma unroll
      for (int n = 0; n < 4; ++n)
        acc[m][n] = __builtin_amdgcn_mfma_f32_16x16x32_bf16(af[m], bfv[n], acc[m][n], 0, 0, 0);
    ca0 = na0; ca1 = na1; cb0 = nb0; cb1 = nb1;
    cur ^= 1;
  }
#pragma unroll
  for (int m = 0; m < 4; ++m)
#pragma unroll
    for (int n = 0; n < 4; ++n)
#pragma unroll
      for (int i = 0; i < 4; ++i)
        atomicAdd(&grad[(size_t)(vd0 + wr + (m << 4) + (fq << 2) + i) * 512
                        + kd0 + wc + (n << 4) + fr], acc[m][n][i]);
}

// ---------------------------------------------------------------------------
// c1a: reduce colk partials (256) and colv partials (256) -> colk/colv[512]
// ---------------------------------------------------------------------------
__global__ __launch_bounds__(256) void c1a_redcols(
    const float* __restrict__ ckp, const float* __restrict__ cvp,
    float* __restrict__ colk, float* __restrict__ colv)
{
  __shared__ float red[8][32];
  const int t = threadIdx.x, b = blockIdx.x;
  const int mtx = b >> 4;
  const int c = ((b & 15) << 5) + (t & 31);
  const int pg = t >> 5;
  const float* src = mtx ? cvp : ckp;
  float s = 0.f;
  for (int p = pg; p < 256; p += 8) s += src[(size_t)p * 512 + c];
  red[pg][t & 31] = s;
  __syncthreads();
  if (pg == 0) {
    float tot = 0.f;
#pragma unroll
    for (int j = 0; j < 8; ++j) tot += red[j][t & 31];
    (mtx ? colv : colk)[c] = tot;
  }
}

// ---------------------------------------------------------------------------
// c1b: gates + loss finalize (1 block); zeroes norm accumulators.
// ---------------------------------------------------------------------------
__global__ __launch_bounds__(256) void c1b_gates(
    const float* __restrict__ gw, const float* __restrict__ gb,
    const float* __restrict__ colk, const float* __restrict__ colv,
    const float* __restrict__ lossp, float* __restrict__ scal,
    float* __restrict__ outp)
{
  __shared__ float red3[3][4];
  __shared__ float redl[4];
  const int t = threadIdx.x, lane = t & 63, wvi = t >> 6;
  float p3[3] = {0.f, 0.f, 0.f};
  for (int j = t; j < 1024; j += 256) {
    const float kv = (j < 512 ? colk[j] : colv[j - 512]) * (1.0f / 32768.0f);
    p3[0] += kv * gw[j];
    p3[1] += kv * gw[1024 + j];
    p3[2] += kv * gw[2048 + j];
  }
  float ls = lossp[t] + lossp[256 + t] + lossp[512 + t] + lossp[768 + t];
#pragma unroll
  for (int o = 32; o; o >>= 1) {
    ls += __shfl_xor(ls, o);
#pragma unroll
    for (int g = 0; g < 3; ++g) p3[g] += __shfl_xor(p3[g], o);
  }
  if (lane == 0) {
    red3[0][wvi] = p3[0]; red3[1][wvi] = p3[1]; red3[2][wvi] = p3[2];
    redl[wvi] = ls;
  }
  __syncthreads();
  if (t == 0) {
    const float s0 = red3[0][0] + red3[0][1] + red3[0][2] + red3[0][3] + gb[0];
    const float s1 = red3[1][0] + red3[1][1] + red3[1][2] + red3[1][3] + gb[1];
    const float s2 = red3[2][0] + red3[2][1] + red3[2][2] + red3[2][3] + gb[2];
    const float alpha = 1.0f / (1.0f + expf(-s0));
    const float eta   = 1.0f / (1.0f + expf(-s1));
    const float theta = 1.0f / (1.0f + expf(-s2));
    scal[1] = 0.f; scal[2] = 0.f;
    scal[3] = alpha; scal[4] = eta; scal[5] = theta;
    outp[OUT_LOSS] = (redl[0] + redl[1] + redl[2] + redl[3]) * (1.0f / 16777216.0f);
    outp[OUT_ALPHA]     = alpha;
    outp[OUT_ALPHA + 1] = eta;
    outp[OUT_ALPHA + 2] = theta;
  }
}

__device__ __forceinline__ void block_atomic_sumsq(float sq, float* target) {
  __shared__ float red[4];
#pragma unroll
  for (int o = 32; o; o >>= 1) sq += __shfl_xor(sq, o);
  if ((threadIdx.x & 63) == 0) red[threadIdx.x >> 6] = sq;
  __syncthreads();
  if (threadIdx.x == 0) atomicAdd(target, red[0] + red[1] + red[2] + red[3]);
}

// c2: m_raw = eta*S - 0.005*theta*clip(grad); accumulate ||m||^2
__global__ __launch_bounds__(256) void c2_mom(
    const float* __restrict__ grad, const float* __restrict__ S,
    float* scal, float* __restrict__ m_raw)
{
  const float eta = scal[4];
  const float cth = 0.005f * scal[5];
  const int i = ((blockIdx.x << 8) + threadIdx.x) << 2;
  const float4_t g = *reinterpret_cast<const float4_t*>(&grad[i]);
  const float4_t s = *reinterpret_cast<const float4_t*>(&S[i]);
  float4_t m; float sq = 0.f;
#pragma unroll
  for (int j = 0; j < 4; ++j) {
    float gj = g[j] * (2.0f / 16777216.0f);
    gj = fminf(1.0f, fmaxf(-1.0f, gj));
    m[j] = eta * s[j] - cth * gj;
    sq += m[j] * m[j];
  }
  *reinterpret_cast<float4_t*>(&m_raw[i]) = m;
  block_atomic_sumsq(sq, &scal[1]);
}

// c3: clip momentum -> out; w_raw = (1-alpha)*W + m; accumulate ||w||^2
__global__ __launch_bounds__(256) void c3_wt(
    const float* __restrict__ m_raw, const float* __restrict__ memw,
    float* scal, float* __restrict__ w_raw, float* __restrict__ outp)
{
  const float nm = sqrtf(scal[1]);
  const float sm = nm > 5.0f ? 5.0f / (nm + 1e-8f) : 1.0f;
  const float oma = 1.0f - scal[3];
  const int i = ((blockIdx.x << 8) + threadIdx.x) << 2;
  const float4_t mr = *reinterpret_cast<const float4_t*>(&m_raw[i]);
  const float4_t wi = *reinterpret_cast<const float4_t*>(&memw[i]);
  float4_t w; float sq = 0.f;
#pragma unroll
  for (int j = 0; j < 4; ++j) {
    const float m = mr[j] * sm;
    outp[OUT_MOM + i + j] = m;
    w[j] = oma * wi[j] + m;
    sq += w[j] * w[j];
  }
  *reinterpret_cast<float4_t*>(&w_raw[i]) = w;
  block_atomic_sumsq(sq, &scal[2]);
}

// c4: clip weight -> out
__global__ __launch_bounds__(256) void c4_wt(
    const float* __restrict__ w_raw, const float* __restrict__ scal,
    float* __restrict__ outp)
{
  const float nw = sqrtf(scal[2]);
  const float sw = nw > 5.0f ? 5.0f / (nw + 1e-8f) : 1.0f;
  const int i = ((blockIdx.x << 8) + threadIdx.x) << 2;
  const float4_t w = *reinterpret_cast<const float4_t*>(&w_raw[i]);
#pragma unroll
  for (int j = 0; j < 4; ++j)
    outp[OUT_W + i + j] = w[j] * sw;
}

// ---------------------------------------------------------------------------
extern "C" void kernel_launch(void* const* d_in, const int* in_sizes, int n_in,
                              void* d_out, int out_size, void* d_ws, size_t ws_size,
                              hipStream_t stream)
{
  const float* Kp = (const float*)d_in[0];
  const float* Vp = (const float*)d_in[1];
  const float* Wp = (const float*)d_in[2];
  const float* GW = (const float*)d_in[3];
  const float* GB = (const float*)d_in[4];
  const float* Sp = (const float*)d_in[5];
  float* outp = (float*)d_out;
  char* ws = (char*)d_ws;

  float* grad            = (float*)(ws + OFF_GRAD);
  float* colk_part       = (float*)(ws + OFF_CKP);
  float* colv_part       = (float*)(ws + OFF_CVP);
  float* loss_part       = (float*)(ws + OFF_LOSSP);
  float* colk            = (float*)(ws + OFF_COLK);
  float* colv            = (float*)(ws + OFF_COLV);
  float* scal            = (float*)(ws + OFF_SCAL);
  unsigned short* w16    = (unsigned short*)(ws + OFF_W16);
  unsigned short* k16    = (unsigned short*)(ws + OFF_K16);
  unsigned short* diff16 = (unsigned short*)(ws + OFF_DIFF);
  float* m_raw           = (float*)(ws + OFF_MRAW);
  float* w_raw           = (float*)(ws + OFF_WRAW);

  k1_convert<<<288, 256, 0, stream>>>(Kp, Wp, k16, w16, colk_part, grad);
  k2_gemm<<<1024, 256, 0, stream>>>(k16, w16, Vp, outp, diff16, colv_part, loss_part);
  k3_grad<<<512, 256, 0, stream>>>(diff16, k16, grad);
  c1a_redcols<<<32, 256, 0, stream>>>(colk_part, colv_part, colk, colv);
  c1b_gates<<<1, 256, 0, stream>>>(GW, GB, colk, colv, loss_part, scal, outp);
  c2_mom<<<256, 256, 0, stream>>>(grad, Sp, scal, m_raw);
  c3_wt<<<256, 256, 0, stream>>>(m_raw, Wp, scal, w_raw, outp);
  c4_wt<<<256, 256, 0, stream>>>(w_raw, scal, outp);
}

// Round 9
// 163.860 us; speedup vs baseline: 1.2945x; 1.0245x over previous
//
#include <hip/hip_runtime.h>
#include <math.h>

// ---------------------------------------------------------------------------
// TitansMemoryModule fused update, MI355X (gfx950) — round 9
//   K1: f32->bf16 convert of K,W + colk partials + grad zeroing (no memset)
//   K2: round-2 verbatim GEMM (77us proven)
//   K3: grad = diff^T @ k — TRUE software pipeline: counted-waitcnt barrier
//       (lgkmcnt-only drain; global loads stay in flight across s_barrier),
//       2-deep reg prefetch with named reg sets, dbuf LDS. Algebra verbatim.
//   c1a/c1b: reductions + gates; c2-c4: momentum/weight + norm clips
// Output (flat f32): retrieved[16777216], loss, new_weight[262144],
//   new_momentum[262144], alpha, eta, theta
// ---------------------------------------------------------------------------

typedef __bf16 bf16x8 __attribute__((ext_vector_type(8)));
typedef float f32x4 __attribute__((ext_vector_type(4)));
typedef float float4_t __attribute__((ext_vector_type(4)));
typedef unsigned short ushort4_t __attribute__((ext_vector_type(4)));
typedef unsigned short ushort8_t __attribute__((ext_vector_type(8)));

#define OUT_LOSS   16777216
#define OUT_W      16777217
#define OUT_MOM    17039361
#define OUT_ALPHA  17301505

// ws layout (bytes)
#define OFF_GRAD   0u           // grad accum [512][512] f32 = 1 MB [K1 zeroes]
#define OFF_CKP    1048576u     // colk_part [256][512] f32 = 512 KB (K1)
#define OFF_CVP    1572864u     // colv_part [256][512] f32 = 512 KB (K2)
#define OFF_LOSSP  2097152u     // loss_part [1024] f32 (plain stores, K2)
#define OFF_COLK   2105344u     // colk [512] f32
#define OFF_COLV   2107392u     // colv [512] f32
#define OFF_SCAL   2109440u     // scal[16]: 1=||m||^2 2=||w||^2 3=a 4=e 5=t
#define OFF_W16    2109504u     // 512 KB bf16 W
#define OFF_K16    2633792u     // 32 MB bf16 K (row-major)
#define OFF_DIFF   36188224u    // 32 MB bf16 diff (row-major)
#define OFF_MRAW   OFF_K16      // m_raw aliases k16 (dead after K3)
#define OFF_WRAW   (OFF_K16 + 1048576u)

__device__ __forceinline__ ushort4_t cvt4(float4_t v) {
  union { __bf16 b; unsigned short u; } c0, c1, c2, c3;
  c0.b = (__bf16)v.x; c1.b = (__bf16)v.y; c2.b = (__bf16)v.z; c3.b = (__bf16)v.w;
  ushort4_t h; h.x = c0.u; h.y = c1.u; h.z = c2.u; h.w = c3.u;
  return h;
}

__device__ __forceinline__ void gload_lds16(const unsigned short* g, unsigned short* l) {
  __builtin_amdgcn_global_load_lds(
      (const __attribute__((address_space(1))) unsigned int*)g,
      (__attribute__((address_space(3))) unsigned int*)l, 16, 0, 0);
}

// ---------------------------------------------------------------------------
// K1: blocks 0..255 convert K (128 rows each) + colk partials;
// 256..271 convert W (32 rows each); 272..287 zero grad (64 KB each).
// ---------------------------------------------------------------------------
__global__ __launch_bounds__(256) void k1_convert(
    const float* __restrict__ Kp, const float* __restrict__ Wp,
    unsigned short* __restrict__ k16, unsigned short* __restrict__ w16,
    float* __restrict__ colk_part, float* __restrict__ grad)
{
  __shared__ float cp[512];
  const int t = threadIdx.x;
  const int cg = t & 127;
  const int g = t >> 7;
  const int b = blockIdx.x;
  if (b < 256) {
    const int r0 = b << 7;
    float p0 = 0.f, p1 = 0.f, p2 = 0.f, p3 = 0.f;
#pragma unroll 4
    for (int rr = g; rr < 128; rr += 2) {
      const size_t off = (size_t)(r0 + rr) * 512 + (cg << 2);
      const float4_t v = *reinterpret_cast<const float4_t*>(&Kp[off]);
      *reinterpret_cast<ushort4_t*>(&k16[off]) = cvt4(v);
      p0 += v.x; p1 += v.y; p2 += v.z; p3 += v.w;
    }
    if (g == 1) {
      cp[(cg << 2) + 0] = p0; cp[(cg << 2) + 1] = p1;
      cp[(cg << 2) + 2] = p2; cp[(cg << 2) + 3] = p3;
    }
    __syncthreads();
    if (g == 0) {
      colk_part[(size_t)b * 512 + (cg << 2) + 0] = p0 + cp[(cg << 2) + 0];
      colk_part[(size_t)b * 512 + (cg << 2) + 1] = p1 + cp[(cg << 2) + 1];
      colk_part[(size_t)b * 512 + (cg << 2) + 2] = p2 + cp[(cg << 2) + 2];
      colk_part[(size_t)b * 512 + (cg << 2) + 3] = p3 + cp[(cg << 2) + 3];
    }
  } else if (b < 272) {
    const int r0 = (b - 256) << 5;
#pragma unroll 4
    for (int rr = g; rr < 32; rr += 2) {
      const size_t off = (size_t)(r0 + rr) * 512 + (cg << 2);
      const float4_t v = *reinterpret_cast<const float4_t*>(&Wp[off]);
      *reinterpret_cast<ushort4_t*>(&w16[off]) = cvt4(v);
    }
  } else {
    const int base = (b - 272) << 14;
    const float4_t z = (float4_t){0.f, 0.f, 0.f, 0.f};
#pragma unroll
    for (int j = 0; j < 16; ++j)
      *reinterpret_cast<float4_t*>(&grad[base + (j << 10) + (t << 2)]) = z;
  }
}

// ---------------------------------------------------------------------------
// K2: retrieved = k16 @ w16^T.  Round-2 verbatim (77us proven).
// ---------------------------------------------------------------------------
__global__ __launch_bounds__(256) void k2_gemm(
    const unsigned short* __restrict__ k16, const unsigned short* __restrict__ w16,
    const float* __restrict__ Vp, float* __restrict__ outp,
    unsigned short* __restrict__ diff16,
    float* __restrict__ colv_part, float* __restrict__ loss_part)
{
  __shared__ __align__(16) unsigned short As[8192];
  __shared__ __align__(16) unsigned short Bs[8192];
  __shared__ float redc[256];
  __shared__ float redl[4];

  const int t = threadIdx.x, lane = t & 63, wv = t >> 6;
  const int tile = (blockIdx.x & 7) * 128 + (blockIdx.x >> 3);
  const int rt = tile >> 2, vt = tile & 3;
  const int row0 = rt << 7, vd0 = vt << 7;

  f32x4 acc[4][4];
#pragma unroll
  for (int m = 0; m < 4; ++m)
#pragma unroll
    for (int n = 0; n < 4; ++n)
      acc[m][n] = (f32x4){0.f, 0.f, 0.f, 0.f};

  const int srow = (wv << 3) + (lane >> 3);
  const int scol = (lane & 7) << 3;
  const unsigned short* pA = k16 + (size_t)(row0 + srow) * 512 + scol;
  const unsigned short* pB = w16 + (size_t)(vd0 + srow) * 512 + scol;
  unsigned short* lA = &As[wv << 9];
  unsigned short* lB = &Bs[wv << 9];

  const int fr = lane & 15, fq = lane >> 4;
  const int wr = (wv >> 1) << 6, wc = (wv & 1) << 6;

  for (int kk0 = 0; kk0 < 512; kk0 += 64) {
#pragma unroll
    for (int i = 0; i < 4; ++i) {
      gload_lds16(pA + (i << 14) + kk0, lA + (i << 11));
      gload_lds16(pB + (i << 14) + kk0, lB + (i << 11));
    }
    __syncthreads();
#pragma unroll
    for (int kk = 0; kk < 64; kk += 32) {
      const int co = kk + (fq << 3);
      bf16x8 af[4], bfv[4];
#pragma unroll
      for (int m = 0; m < 4; ++m)
        af[m] = *reinterpret_cast<const bf16x8*>(&As[((wr + (m << 4) + fr) << 6) + co]);
#pragma unroll
      for (int n = 0; n < 4; ++n)
        bfv[n] = *reinterpret_cast<const bf16x8*>(&Bs[((wc + (n << 4) + fr) << 6) + co]);
#pragma unroll
      for (int m = 0; m < 4; ++m)
#pragma unroll
        for (int n = 0; n < 4; ++n)
          acc[m][n] = __builtin_amdgcn_mfma_f32_16x16x32_bf16(af[m], bfv[n], acc[m][n], 0, 0, 0);
    }
    __syncthreads();
  }

  float lsum = 0.f;
  float vcs[4] = {0.f, 0.f, 0.f, 0.f};
#pragma unroll
  for (int m = 0; m < 4; ++m) {
#pragma unroll
    for (int n = 0; n < 4; ++n) {
#pragma unroll
      for (int i = 0; i < 4; ++i) {
        const int gr = row0 + wr + (m << 4) + (fq << 2) + i;
        const int gc = vd0 + wc + (n << 4) + fr;
        const size_t oi = (size_t)gr * 512 + gc;
        const float rv = acc[m][n][i];
        outp[oi] = rv;
        const float vv = Vp[oi];
        const float d = rv - vv;
        lsum += d * d;
        vcs[n] += vv;
        union { __bf16 b; unsigned short u; } cd; cd.b = (__bf16)d;
        diff16[oi] = cd.u;
      }
    }
  }
#pragma unroll
  for (int o = 32; o; o >>= 1) lsum += __shfl_xor(lsum, o);
  if (lane == 0) redl[wv] = lsum;
#pragma unroll
  for (int n = 0; n < 4; ++n) {
    vcs[n] += __shfl_xor(vcs[n], 16);
    vcs[n] += __shfl_xor(vcs[n], 32);
  }
  if (fq == 0) {
#pragma unroll
    for (int n = 0; n < 4; ++n)
      redc[(wv << 6) + (n << 4) + fr] = vcs[n];
  }
  __syncthreads();
  if (t < 128) {
    const int side = t >> 6, lc = t & 63;
    colv_part[(size_t)rt * 512 + vd0 + t] =
        redc[side * 64 + lc] + redc[(side + 2) * 64 + lc];
  }
  if (t == 0)
    loss_part[tile] = redl[0] + redl[1] + redl[2] + redl[3];
}

// ---------------------------------------------------------------------------
// K3: grad += diff^T @ k. Counted-waitcnt pipeline: lgkmcnt-only barrier
// (global loads to regs stay in flight across s_barrier); 2-deep prefetch
// with named reg sets; dbuf LDS. Staging/read algebra = round-2 verbatim.
// 512 blocks, 32 K-chunks x 16 tiles, XCD-grouped.
// ---------------------------------------------------------------------------
__global__ __launch_bounds__(256) void k3_grad(
    const unsigned short* __restrict__ diff16,
    const unsigned short* __restrict__ k16,
    float* __restrict__ grad)
{
  __shared__ __align__(16) unsigned short At[2][128][40];
  __shared__ __align__(16) unsigned short Bt[2][128][40];
  const int t = threadIdx.x, lane = t & 63, wv = t >> 6;
  const int b = blockIdx.x;
  const int x = b & 7;
  const int q = b >> 3;
  const int tile = q & 15;
  const int kc = ((q >> 4) << 3) | x;       // all 16 tiles of kc share an XCD
  const int vd0 = (tile & 3) << 7;
  const int kd0 = (tile >> 2) << 7;
  const size_t r0 = (size_t)kc << 10;       // 1024 rows, 32 steps of 32

  f32x4 acc[4][4];
#pragma unroll
  for (int m = 0; m < 4; ++m)
#pragma unroll
    for (int n = 0; n < 4; ++n)
      acc[m][n] = (f32x4){0.f, 0.f, 0.f, 0.f};

  const int dr = t >> 3;
  const int c0 = (t & 7) << 4;
  const int wr = (wv >> 1) << 6, wc = (wv & 1) << 6;
  const int fr = lane & 15, fq = lane >> 4;
  const int swz = ((c0 >> 4) & 3) << 3;
  const int drs = dr ^ swz;

#define K3_LOAD(s, A0, A1, B0, B1) do {                                     \
    const size_t ro_ = (r0 + ((size_t)(s) << 5) + dr) << 9;                 \
    A0 = *reinterpret_cast<const ushort8_t*>(&diff16[ro_ + vd0 + c0]);      \
    A1 = *reinterpret_cast<const ushort8_t*>(&diff16[ro_ + vd0 + c0 + 8]);  \
    B0 = *reinterpret_cast<const ushort8_t*>(&k16[ro_ + kd0 + c0]);         \
    B1 = *reinterpret_cast<const ushort8_t*>(&k16[ro_ + kd0 + c0 + 8]);     \
  } while (0)

#define K3_WRITE(buf, A0, A1, B0, B1) do {                                  \
    _Pragma("unroll")                                                       \
    for (int j = 0; j < 8; ++j) {                                           \
      At[buf][c0 + j][drs] = A0[j];                                         \
      At[buf][c0 + 8 + j][drs] = A1[j];                                     \
      Bt[buf][c0 + j][drs] = B0[j];                                         \
      Bt[buf][c0 + 8 + j][drs] = B1[j];                                     \
    } } while (0)

#define K3_MFMA(buf) do {                                                   \
    bf16x8 af[4], bfv[4];                                                   \
    _Pragma("unroll")                                                       \
    for (int m = 0; m < 4; ++m) {                                           \
      const int rA = wr + (m << 4) + fr;                                    \
      af[m] = *reinterpret_cast<const bf16x8*>(                             \
          &At[buf][rA][(fq ^ ((rA >> 4) & 3)) << 3]);                       \
    }                                                                       \
    _Pragma("unroll")                                                       \
    for (int n = 0; n < 4; ++n) {                                           \
      const int rB = wc + (n << 4) + fr;                                    \
      bfv[n] = *reinterpret_cast<const bf16x8*>(                            \
          &Bt[buf][rB][(fq ^ ((rB >> 4) & 3)) << 3]);                       \
    }                                                                       \
    _Pragma("unroll")                                                       \
    for (int m = 0; m < 4; ++m)                                             \
      _Pragma("unroll")                                                     \
      for (int n = 0; n < 4; ++n)                                           \
        acc[m][n] = __builtin_amdgcn_mfma_f32_16x16x32_bf16(                \
            af[m], bfv[n], acc[m][n], 0, 0, 0);                             \
  } while (0)

// lgkmcnt-only drain: LDS writes visible, global loads stay in flight
#define K3_LBAR() do {                                                      \
    asm volatile("s_waitcnt lgkmcnt(0)" ::: "memory");                      \
    __builtin_amdgcn_s_barrier();                                           \
  } while (0)

  ushort8_t a0A, a1A, b0A, b1A, a0B, a1B, b0B, b1B;
  // prologue: data(0) -> buf0; data(1) in regsB
  K3_LOAD(0, a0A, a1A, b0A, b1A);
  K3_WRITE(0, a0A, a1A, b0A, b1A);
  K3_LOAD(1, a0B, a1B, b0B, b1B);
  K3_LBAR();

  // steady state: 15 double-steps cover s = 0..29
#pragma unroll 1
  for (int it = 0; it < 15; ++it) {
    const int s = it << 1;
    // step s (even): issue loads(s+2); write data(s+1)->buf1; MFMA buf0
    K3_LOAD(s + 2, a0A, a1A, b0A, b1A);
    K3_WRITE(1, a0B, a1B, b0B, b1B);
    K3_MFMA(0);
    K3_LBAR();
    // step s+1 (odd): issue loads(s+3); write data(s+2)->buf0; MFMA buf1
    K3_LOAD(s + 3, a0B, a1B, b0B, b1B);
    K3_WRITE(0, a0A, a1A, b0A, b1A);
    K3_MFMA(1);
    K3_LBAR();
  }
  // epilogue: s=30: write data(31)->buf1; MFMA buf0; s=31: MFMA buf1
  K3_WRITE(1, a0B, a1B, b0B, b1B);
  K3_MFMA(0);
  K3_LBAR();
  K3_MFMA(1);

#undef K3_LOAD
#undef K3_WRITE
#undef K3_MFMA
#undef K3_LBAR

#pragma unroll
  for (int m = 0; m < 4; ++m)
#pragma unroll
    for (int n = 0; n < 4; ++n)
#pragma unroll
      for (int i = 0; i < 4; ++i)
        atomicAdd(&grad[(size_t)(vd0 + wr + (m << 4) + (fq << 2) + i) * 512
                        + kd0 + wc + (n << 4) + fr], acc[m][n][i]);
}

// ---------------------------------------------------------------------------
// c1a: reduce colk partials (256) and colv partials (256) -> colk/colv[512]
// ---------------------------------------------------------------------------
__global__ __launch_bounds__(256) void c1a_redcols(
    const float* __restrict__ ckp, const float* __restrict__ cvp,
    float* __restrict__ colk, float* __restrict__ colv)
{
  __shared__ float red[8][32];
  const int t = threadIdx.x, b = blockIdx.x;
  const int mtx = b >> 4;
  const int c = ((b & 15) << 5) + (t & 31);
  const int pg = t >> 5;
  const float* src = mtx ? cvp : ckp;
  float s = 0.f;
  for (int p = pg; p < 256; p += 8) s += src[(size_t)p * 512 + c];
  red[pg][t & 31] = s;
  __syncthreads();
  if (pg == 0) {
    float tot = 0.f;
#pragma unroll
    for (int j = 0; j < 8; ++j) tot += red[j][t & 31];
    (mtx ? colv : colk)[c] = tot;
  }
}

// ---------------------------------------------------------------------------
// c1b: gates + loss finalize (1 block); zeroes norm accumulators.
// ---------------------------------------------------------------------------
__global__ __launch_bounds__(256) void c1b_gates(
    const float* __restrict__ gw, const float* __restrict__ gb,
    const float* __restrict__ colk, const float* __restrict__ colv,
    const float* __restrict__ lossp, float* __restrict__ scal,
    float* __restrict__ outp)
{
  __shared__ float red3[3][4];
  __shared__ float redl[4];
  const int t = threadIdx.x, lane = t & 63, wvi = t >> 6;
  float p3[3] = {0.f, 0.f, 0.f};
  for (int j = t; j < 1024; j += 256) {
    const float kv = (j < 512 ? colk[j] : colv[j - 512]) * (1.0f / 32768.0f);
    p3[0] += kv * gw[j];
    p3[1] += kv * gw[1024 + j];
    p3[2] += kv * gw[2048 + j];
  }
  float ls = lossp[t] + lossp[256 + t] + lossp[512 + t] + lossp[768 + t];
#pragma unroll
  for (int o = 32; o; o >>= 1) {
    ls += __shfl_xor(ls, o);
#pragma unroll
    for (int g = 0; g < 3; ++g) p3[g] += __shfl_xor(p3[g], o);
  }
  if (lane == 0) {
    red3[0][wvi] = p3[0]; red3[1][wvi] = p3[1]; red3[2][wvi] = p3[2];
    redl[wvi] = ls;
  }
  __syncthreads();
  if (t == 0) {
    const float s0 = red3[0][0] + red3[0][1] + red3[0][2] + red3[0][3] + gb[0];
    const float s1 = red3[1][0] + red3[1][1] + red3[1][2] + red3[1][3] + gb[1];
    const float s2 = red3[2][0] + red3[2][1] + red3[2][2] + red3[2][3] + gb[2];
    const float alpha = 1.0f / (1.0f + expf(-s0));
    const float eta   = 1.0f / (1.0f + expf(-s1));
    const float theta = 1.0f / (1.0f + expf(-s2));
    scal[1] = 0.f; scal[2] = 0.f;
    scal[3] = alpha; scal[4] = eta; scal[5] = theta;
    outp[OUT_LOSS] = (redl[0] + redl[1] + redl[2] + redl[3]) * (1.0f / 16777216.0f);
    outp[OUT_ALPHA]     = alpha;
    outp[OUT_ALPHA + 1] = eta;
    outp[OUT_ALPHA + 2] = theta;
  }
}

__device__ __forceinline__ void block_atomic_sumsq(float sq, float* target) {
  __shared__ float red[4];
#pragma unroll
  for (int o = 32; o; o >>= 1) sq += __shfl_xor(sq, o);
  if ((threadIdx.x & 63) == 0) red[threadIdx.x >> 6] = sq;
  __syncthreads();
  if (threadIdx.x == 0) atomicAdd(target, red[0] + red[1] + red[2] + red[3]);
}

// c2: m_raw = eta*S - 0.005*theta*clip(grad); accumulate ||m||^2
__global__ __launch_bounds__(256) void c2_mom(
    const float* __restrict__ grad, const float* __restrict__ S,
    float* scal, float* __restrict__ m_raw)
{
  const float eta = scal[4];
  const float cth = 0.005f * scal[5];
  const int i = ((blockIdx.x << 8) + threadIdx.x) << 2;
  const float4_t g = *reinterpret_cast<const float4_t*>(&grad[i]);
  const float4_t s = *reinterpret_cast<const float4_t*>(&S[i]);
  float4_t m; float sq = 0.f;
#pragma unroll
  for (int j = 0; j < 4; ++j) {
    float gj = g[j] * (2.0f / 16777216.0f);
    gj = fminf(1.0f, fmaxf(-1.0f, gj));
    m[j] = eta * s[j] - cth * gj;
    sq += m[j] * m[j];
  }
  *reinterpret_cast<float4_t*>(&m_raw[i]) = m;
  block_atomic_sumsq(sq, &scal[1]);
}

// c3: clip momentum -> out; w_raw = (1-alpha)*W + m; accumulate ||w||^2
__global__ __launch_bounds__(256) void c3_wt(
    const float* __restrict__ m_raw, const float* __restrict__ memw,
    float* scal, float* __restrict__ w_raw, float* __restrict__ outp)
{
  const float nm = sqrtf(scal[1]);
  const float sm = nm > 5.0f ? 5.0f / (nm + 1e-8f) : 1.0f;
  const float oma = 1.0f - scal[3];
  const int i = ((blockIdx.x << 8) + threadIdx.x) << 2;
  const float4_t mr = *reinterpret_cast<const float4_t*>(&m_raw[i]);
  const float4_t wi = *reinterpret_cast<const float4_t*>(&memw[i]);
  float4_t w; float sq = 0.f;
#pragma unroll
  for (int j = 0; j < 4; ++j) {
    const float m = mr[j] * sm;
    outp[OUT_MOM + i + j] = m;
    w[j] = oma * wi[j] + m;
    sq += w[j] * w[j];
  }
  *reinterpret_cast<float4_t*>(&w_raw[i]) = w;
  block_atomic_sumsq(sq, &scal[2]);
}

// c4: clip weight -> out
__global__ __launch_bounds__(256) void c4_wt(
    const float* __restrict__ w_raw, const float* __restrict__ scal,
    float* __restrict__ outp)
{
  const float nw = sqrtf(scal[2]);
  const float sw = nw > 5.0f ? 5.0f / (nw + 1e-8f) : 1.0f;
  const int i = ((blockIdx.x << 8) + threadIdx.x) << 2;
  const float4_t w = *reinterpret_cast<const float4_t*>(&w_raw[i]);
#pragma unroll
  for (int j = 0; j < 4; ++j)
    outp[OUT_W + i + j] = w[j] * sw;
}

// ---------------------------------------------------------------------------
extern "C" void kernel_launch(void* const* d_in, const int* in_sizes, int n_in,
                              void* d_out, int out_size, void* d_ws, size_t ws_size,
                              hipStream_t stream)
{
  const float* Kp = (const float*)d_in[0];
  const float* Vp = (const float*)d_in[1];
  const float* Wp = (const float*)d_in[2];
  const float* GW = (const float*)d_in[3];
  const float* GB = (const float*)d_in[4];
  const float* Sp = (const float*)d_in[5];
  float* outp = (float*)d_out;
  char* ws = (char*)d_ws;

  float* grad            = (float*)(ws + OFF_GRAD);
  float* colk_part       = (float*)(ws + OFF_CKP);
  float* colv_part       = (float*)(ws + OFF_CVP);
  float* loss_part       = (float*)(ws + OFF_LOSSP);
  float* colk            = (float*)(ws + OFF_COLK);
  float* colv            = (float*)(ws + OFF_COLV);
  float* scal            = (float*)(ws + OFF_SCAL);
  unsigned short* w16    = (unsigned short*)(ws + OFF_W16);
  unsigned short* k16    = (unsigned short*)(ws + OFF_K16);
  unsigned short* diff16 = (unsigned short*)(ws + OFF_DIFF);
  float* m_raw           = (float*)(ws + OFF_MRAW);
  float* w_raw           = (float*)(ws + OFF_WRAW);

  k1_convert<<<288, 256, 0, stream>>>(Kp, Wp, k16, w16, colk_part, grad);
  k2_gemm<<<1024, 256, 0, stream>>>(k16, w16, Vp, outp, diff16, colv_part, loss_part);
  k3_grad<<<512, 256, 0, stream>>>(diff16, k16, grad);
  c1a_redcols<<<32, 256, 0, stream>>>(colk_part, colv_part, colk, colv);
  c1b_gates<<<1, 256, 0, stream>>>(GW, GB, colk, colv, loss_part, scal, outp);
  c2_mom<<<256, 256, 0, stream>>>(grad, Sp, scal, m_raw);
  c3_wt<<<256, 256, 0, stream>>>(m_raw, Wp, scal, w_raw, outp);
  c4_wt<<<256, 256, 0, stream>>>(w_raw, scal, outp);
}

// Round 10
// 153.110 us; speedup vs baseline: 1.3854x; 1.0702x over previous
//
#include <hip/hip_runtime.h>
#include <math.h>

// ---------------------------------------------------------------------------
// TitansMemoryModule fused update, MI355X (gfx950) — round 10
//   K1: pure f32->bf16 convert of K,W (1040 blocks, 4/CU MLP) + grad/scal zero
//   K2: round-2 verbatim GEMM (77us proven)
//   K3: grad = diff^T @ k (r9 lgkmcnt pipeline) + colk partials fused into
//       the staging-write phase (r3-proven pattern)
//   cR: colk/colv partial reduction + 6 dot products (SS,Sg,gg,WW,WS,Wg)
//   c1b: gates + loss + ALL norm scalars via closed-form expansion
//   cF: single pass -> new_momentum AND new_weight
// Output (flat f32): retrieved[16777216], loss, new_weight[262144],
//   new_momentum[262144], alpha, eta, theta
// ---------------------------------------------------------------------------

typedef __bf16 bf16x8 __attribute__((ext_vector_type(8)));
typedef float f32x4 __attribute__((ext_vector_type(4)));
typedef float float4_t __attribute__((ext_vector_type(4)));
typedef unsigned short ushort4_t __attribute__((ext_vector_type(4)));
typedef unsigned short ushort8_t __attribute__((ext_vector_type(8)));

#define OUT_LOSS   16777216
#define OUT_W      16777217
#define OUT_MOM    17039361
#define OUT_ALPHA  17301505

// ws layout (bytes)
#define OFF_GRAD   0u           // grad accum [512][512] f32 = 1 MB [K1 zeroes]
#define OFF_CKP    1048576u     // colk_part [32][512] f32 = 64 KB (K3)
#define OFF_CVP    1572864u     // colv_part [256][512] f32 = 512 KB (K2)
#define OFF_LOSSP  2097152u     // loss_part [1024] f32 (plain stores, K2)
#define OFF_COLK   2105344u     // colk [512] f32
#define OFF_COLV   2107392u     // colv [512] f32
#define OFF_SCAL   2109440u     // scal[16]: 3=a 4=e 5=t 6=sm 7=sw 8..13=dots
#define OFF_W16    2109504u     // 512 KB bf16 W
#define OFF_K16    2633792u     // 32 MB bf16 K (row-major)
#define OFF_DIFF   36188224u    // 32 MB bf16 diff (row-major)

__device__ __forceinline__ ushort4_t cvt4(float4_t v) {
  union { __bf16 b; unsigned short u; } c0, c1, c2, c3;
  c0.b = (__bf16)v.x; c1.b = (__bf16)v.y; c2.b = (__bf16)v.z; c3.b = (__bf16)v.w;
  ushort4_t h; h.x = c0.u; h.y = c1.u; h.z = c2.u; h.w = c3.u;
  return h;
}

__device__ __forceinline__ float bf2f(unsigned short u) {
  return __uint_as_float(((unsigned int)u) << 16);
}

__device__ __forceinline__ void gload_lds16(const unsigned short* g, unsigned short* l) {
  __builtin_amdgcn_global_load_lds(
      (const __attribute__((address_space(1))) unsigned int*)g,
      (__attribute__((address_space(3))) unsigned int*)l, 16, 0, 0);
}

// ---------------------------------------------------------------------------
// K1: pure convert, high MLP. Blocks 0..1023: K (16384 floats each);
// 1024..1039: W; 1040..1055: zero grad (+ scal on block 1040).
// ---------------------------------------------------------------------------
__global__ __launch_bounds__(256) void k1_convert(
    const float* __restrict__ Kp, const float* __restrict__ Wp,
    unsigned short* __restrict__ k16, unsigned short* __restrict__ w16,
    float* __restrict__ grad, float* __restrict__ scal)
{
  const int b = blockIdx.x;
  const int t = threadIdx.x;
  if (b < 1040) {
    const float* src = (b < 1024) ? Kp : Wp;
    unsigned short* dst = (b < 1024) ? k16 : w16;
    const size_t base = (size_t)(b < 1024 ? b : b - 1024) * 16384;
#pragma unroll
    for (int j = 0; j < 8; ++j) {
      const size_t off = base + (size_t)j * 2048 + ((size_t)t << 3);
      const float4_t v0 = *reinterpret_cast<const float4_t*>(&src[off]);
      const float4_t v1 = *reinterpret_cast<const float4_t*>(&src[off + 4]);
      const ushort4_t h0 = cvt4(v0), h1 = cvt4(v1);
      ushort8_t h;
      h[0] = h0.x; h[1] = h0.y; h[2] = h0.z; h[3] = h0.w;
      h[4] = h1.x; h[5] = h1.y; h[6] = h1.z; h[7] = h1.w;
      *reinterpret_cast<ushort8_t*>(&dst[off]) = h;
    }
  } else {
    const int base = (b - 1040) << 14;
    const float4_t z = (float4_t){0.f, 0.f, 0.f, 0.f};
#pragma unroll
    for (int j = 0; j < 16; ++j)
      *reinterpret_cast<float4_t*>(&grad[base + (j << 10) + (t << 2)]) = z;
    if (b == 1040 && t < 16) scal[t] = 0.f;
  }
}

// ---------------------------------------------------------------------------
// K2: retrieved = k16 @ w16^T.  Round-2 verbatim (77us proven).
// ---------------------------------------------------------------------------
__global__ __launch_bounds__(256) void k2_gemm(
    const unsigned short* __restrict__ k16, const unsigned short* __restrict__ w16,
    const float* __restrict__ Vp, float* __restrict__ outp,
    unsigned short* __restrict__ diff16,
    float* __restrict__ colv_part, float* __restrict__ loss_part)
{
  __shared__ __align__(16) unsigned short As[8192];
  __shared__ __align__(16) unsigned short Bs[8192];
  __shared__ float redc[256];
  __shared__ float redl[4];

  const int t = threadIdx.x, lane = t & 63, wv = t >> 6;
  const int tile = (blockIdx.x & 7) * 128 + (blockIdx.x >> 3);
  const int rt = tile >> 2, vt = tile & 3;
  const int row0 = rt << 7, vd0 = vt << 7;

  f32x4 acc[4][4];
#pragma unroll
  for (int m = 0; m < 4; ++m)
#pragma unroll
    for (int n = 0; n < 4; ++n)
      acc[m][n] = (f32x4){0.f, 0.f, 0.f, 0.f};

  const int srow = (wv << 3) + (lane >> 3);
  const int scol = (lane & 7) << 3;
  const unsigned short* pA = k16 + (size_t)(row0 + srow) * 512 + scol;
  const unsigned short* pB = w16 + (size_t)(vd0 + srow) * 512 + scol;
  unsigned short* lA = &As[wv << 9];
  unsigned short* lB = &Bs[wv << 9];

  const int fr = lane & 15, fq = lane >> 4;
  const int wr = (wv >> 1) << 6, wc = (wv & 1) << 6;

  for (int kk0 = 0; kk0 < 512; kk0 += 64) {
#pragma unroll
    for (int i = 0; i < 4; ++i) {
      gload_lds16(pA + (i << 14) + kk0, lA + (i << 11));
      gload_lds16(pB + (i << 14) + kk0, lB + (i << 11));
    }
    __syncthreads();
#pragma unroll
    for (int kk = 0; kk < 64; kk += 32) {
      const int co = kk + (fq << 3);
      bf16x8 af[4], bfv[4];
#pragma unroll
      for (int m = 0; m < 4; ++m)
        af[m] = *reinterpret_cast<const bf16x8*>(&As[((wr + (m << 4) + fr) << 6) + co]);
#pragma unroll
      for (int n = 0; n < 4; ++n)
        bfv[n] = *reinterpret_cast<const bf16x8*>(&Bs[((wc + (n << 4) + fr) << 6) + co]);
#pragma unroll
      for (int m = 0; m < 4; ++m)
#pragma unroll
        for (int n = 0; n < 4; ++n)
          acc[m][n] = __builtin_amdgcn_mfma_f32_16x16x32_bf16(af[m], bfv[n], acc[m][n], 0, 0, 0);
    }
    __syncthreads();
  }

  float lsum = 0.f;
  float vcs[4] = {0.f, 0.f, 0.f, 0.f};
#pragma unroll
  for (int m = 0; m < 4; ++m) {
#pragma unroll
    for (int n = 0; n < 4; ++n) {
#pragma unroll
      for (int i = 0; i < 4; ++i) {
        const int gr = row0 + wr + (m << 4) + (fq << 2) + i;
        const int gc = vd0 + wc + (n << 4) + fr;
        const size_t oi = (size_t)gr * 512 + gc;
        const float rv = acc[m][n][i];
        outp[oi] = rv;
        const float vv = Vp[oi];
        const float d = rv - vv;
        lsum += d * d;
        vcs[n] += vv;
        union { __bf16 b; unsigned short u; } cd; cd.b = (__bf16)d;
        diff16[oi] = cd.u;
      }
    }
  }
#pragma unroll
  for (int o = 32; o; o >>= 1) lsum += __shfl_xor(lsum, o);
  if (lane == 0) redl[wv] = lsum;
#pragma unroll
  for (int n = 0; n < 4; ++n) {
    vcs[n] += __shfl_xor(vcs[n], 16);
    vcs[n] += __shfl_xor(vcs[n], 32);
  }
  if (fq == 0) {
#pragma unroll
    for (int n = 0; n < 4; ++n)
      redc[(wv << 6) + (n << 4) + fr] = vcs[n];
  }
  __syncthreads();
  if (t < 128) {
    const int side = t >> 6, lc = t & 63;
    colv_part[(size_t)rt * 512 + vd0 + t] =
        redc[side * 64 + lc] + redc[(side + 2) * 64 + lc];
  }
  if (t == 0)
    loss_part[tile] = redl[0] + redl[1] + redl[2] + redl[3];
}

// ---------------------------------------------------------------------------
// K3: grad += diff^T @ k. r9 lgkmcnt pipeline + colk partials (vd0==0 blocks,
// accumulated in the staging-write phase so pipeline waits are unaffected).
// ---------------------------------------------------------------------------
__global__ __launch_bounds__(256) void k3_grad(
    const unsigned short* __restrict__ diff16,
    const unsigned short* __restrict__ k16,
    float* __restrict__ grad, float* __restrict__ colk_part)
{
  __shared__ __align__(16) unsigned short At[2][128][40];
  __shared__ __align__(16) unsigned short Bt[2][128][40];
  const int t = threadIdx.x, lane = t & 63, wv = t >> 6;
  const int b = blockIdx.x;
  const int x = b & 7;
  const int q = b >> 3;
  const int tile = q & 15;
  const int kc = ((q >> 4) << 3) | x;
  const int vd0 = (tile & 3) << 7;
  const int kd0 = (tile >> 2) << 7;
  const size_t r0 = (size_t)kc << 10;

  f32x4 acc[4][4];
#pragma unroll
  for (int m = 0; m < 4; ++m)
#pragma unroll
    for (int n = 0; n < 4; ++n)
      acc[m][n] = (f32x4){0.f, 0.f, 0.f, 0.f};

  float ck[16];
#pragma unroll
  for (int j = 0; j < 16; ++j) ck[j] = 0.f;

  const int dr = t >> 3;
  const int c0 = (t & 7) << 4;
  const int wr = (wv >> 1) << 6, wc = (wv & 1) << 6;
  const int fr = lane & 15, fq = lane >> 4;
  const int swz = ((c0 >> 4) & 3) << 3;
  const int drs = dr ^ swz;

#define K3_LOAD(s, A0, A1, B0, B1) do {                                     \
    const size_t ro_ = (r0 + ((size_t)(s) << 5) + dr) << 9;                 \
    A0 = *reinterpret_cast<const ushort8_t*>(&diff16[ro_ + vd0 + c0]);      \
    A1 = *reinterpret_cast<const ushort8_t*>(&diff16[ro_ + vd0 + c0 + 8]);  \
    B0 = *reinterpret_cast<const ushort8_t*>(&k16[ro_ + kd0 + c0]);         \
    B1 = *reinterpret_cast<const ushort8_t*>(&k16[ro_ + kd0 + c0 + 8]);     \
  } while (0)

#define K3_WRITE(buf, A0, A1, B0, B1) do {                                  \
    _Pragma("unroll")                                                       \
    for (int j = 0; j < 8; ++j) {                                           \
      At[buf][c0 + j][drs] = A0[j];                                         \
      At[buf][c0 + 8 + j][drs] = A1[j];                                     \
      Bt[buf][c0 + j][drs] = B0[j];                                         \
      Bt[buf][c0 + 8 + j][drs] = B1[j];                                     \
    }                                                                       \
    if (vd0 == 0) {                                                         \
      _Pragma("unroll")                                                     \
      for (int j = 0; j < 8; ++j) {                                         \
        ck[j] += bf2f(B0[j]); ck[8 + j] += bf2f(B1[j]);                     \
      }                                                                     \
    } } while (0)

#define K3_MFMA(buf) do {                                                   \
    bf16x8 af[4], bfv[4];                                                   \
    _Pragma("unroll")                                                       \
    for (int m = 0; m < 4; ++m) {                                           \
      const int rA = wr + (m << 4) + fr;                                    \
      af[m] = *reinterpret_cast<const bf16x8*>(                             \
          &At[buf][rA][(fq ^ ((rA >> 4) & 3)) << 3]);                       \
    }                                                                       \
    _Pragma("unroll")                                                       \
    for (int n = 0; n < 4; ++n) {                                           \
      const int rB = wc + (n << 4) + fr;                                    \
      bfv[n] = *reinterpret_cast<const bf16x8*>(                            \
          &Bt[buf][rB][(fq ^ ((rB >> 4) & 3)) << 3]);                       \
    }                                                                       \
    _Pragma("unroll")                                                       \
    for (int m = 0; m < 4; ++m)                                             \
      _Pragma("unroll")                                                     \
      for (int n = 0; n < 4; ++n)                                           \
        acc[m][n] = __builtin_amdgcn_mfma_f32_16x16x32_bf16(                \
            af[m], bfv[n], acc[m][n], 0, 0, 0);                             \
  } while (0)

#define K3_LBAR() do {                                                      \
    asm volatile("s_waitcnt lgkmcnt(0)" ::: "memory");                      \
    __builtin_amdgcn_s_barrier();                                           \
  } while (0)

  ushort8_t a0A, a1A, b0A, b1A, a0B, a1B, b0B, b1B;
  K3_LOAD(0, a0A, a1A, b0A, b1A);
  K3_WRITE(0, a0A, a1A, b0A, b1A);
  K3_LOAD(1, a0B, a1B, b0B, b1B);
  K3_LBAR();

#pragma unroll 1
  for (int it = 0; it < 15; ++it) {
    const int s = it << 1;
    K3_LOAD(s + 2, a0A, a1A, b0A, b1A);
    K3_WRITE(1, a0B, a1B, b0B, b1B);
    K3_MFMA(0);
    K3_LBAR();
    K3_LOAD(s + 3, a0B, a1B, b0B, b1B);
    K3_WRITE(0, a0A, a1A, b0A, b1A);
    K3_MFMA(1);
    K3_LBAR();
  }
  K3_WRITE(1, a0B, a1B, b0B, b1B);
  K3_MFMA(0);
  K3_LBAR();
  K3_MFMA(1);

#undef K3_LOAD
#undef K3_WRITE
#undef K3_MFMA
#undef K3_LBAR

#pragma unroll
  for (int m = 0; m < 4; ++m)
#pragma unroll
    for (int n = 0; n < 4; ++n)
#pragma unroll
      for (int i = 0; i < 4; ++i)
        atomicAdd(&grad[(size_t)(vd0 + wr + (m << 4) + (fq << 2) + i) * 512
                        + kd0 + wc + (n << 4) + fr], acc[m][n][i]);

  // colk partials: reduce 8 dr-threads sharing c0 (lanes l^8,16,32), r3-proven
  if (vd0 == 0) {
#pragma unroll
    for (int j = 0; j < 16; ++j) {
      ck[j] += __shfl_xor(ck[j], 8);
      ck[j] += __shfl_xor(ck[j], 16);
      ck[j] += __shfl_xor(ck[j], 32);
    }
    __syncthreads();
    float* cred = (float*)&At[0][0][0];   // reuse LDS (512 f32)
    if (lane < 8) {
#pragma unroll
      for (int j = 0; j < 16; ++j) cred[(wv << 7) + (lane << 4) + j] = ck[j];
    }
    __syncthreads();
    if (t < 128) {
      colk_part[(size_t)kc * 512 + kd0 + t] =
          cred[t] + cred[128 + t] + cred[256 + t] + cred[384 + t];
    }
  }
}

// ---------------------------------------------------------------------------
// cR: blocks 0..31 reduce colk (P=32) / colv (P=256) partials;
// blocks 32..47: 6 dot products {SS,Sg,gg,WW,WS,Wg} -> scal[8..13] atomics.
// ---------------------------------------------------------------------------
__global__ __launch_bounds__(256) void cR_reduce(
    const float* __restrict__ ckp, const float* __restrict__ cvp,
    float* __restrict__ colk, float* __restrict__ colv,
    const float* __restrict__ grad, const float* __restrict__ S,
    const float* __restrict__ Wm, float* __restrict__ scal)
{
  const int t = threadIdx.x, b = blockIdx.x;
  if (b < 32) {
    __shared__ float red[8][32];
    const int mtx = b >> 4;
    const int c = ((b & 15) << 5) + (t & 31);
    const int pg = t >> 5;
    const float* src = mtx ? cvp : ckp;
    const int P = mtx ? 256 : 32;
    float s = 0.f;
    for (int p = pg; p < P; p += 8) s += src[(size_t)p * 512 + c];
    red[pg][t & 31] = s;
    __syncthreads();
    if (pg == 0) {
      float tot = 0.f;
#pragma unroll
      for (int j = 0; j < 8; ++j) tot += red[j][t & 31];
      (mtx ? colv : colk)[c] = tot;
    }
  } else {
    __shared__ float red6[6][4];
    const int qb = b - 32;            // 0..15, 16384 elems each
    float d[6] = {0.f, 0.f, 0.f, 0.f, 0.f, 0.f};
#pragma unroll
    for (int j = 0; j < 16; ++j) {
      const int i = (qb << 14) + (j << 10) + (t << 2);
      const float4_t g4 = *reinterpret_cast<const float4_t*>(&grad[i]);
      const float4_t s4 = *reinterpret_cast<const float4_t*>(&S[i]);
      const float4_t w4 = *reinterpret_cast<const float4_t*>(&Wm[i]);
#pragma unroll
      for (int e = 0; e < 4; ++e) {
        float gt = g4[e] * (2.0f / 16777216.0f);
        gt = fminf(1.0f, fmaxf(-1.0f, gt));
        d[0] += s4[e] * s4[e];    // SS
        d[1] += s4[e] * gt;       // Sg
        d[2] += gt * gt;          // gg
        d[3] += w4[e] * w4[e];    // WW
        d[4] += w4[e] * s4[e];    // WS
        d[5] += w4[e] * gt;       // Wg
      }
    }
    const int lane = t & 63, wvi = t >> 6;
#pragma unroll
    for (int k = 0; k < 6; ++k) {
#pragma unroll
      for (int o = 32; o; o >>= 1) d[k] += __shfl_xor(d[k], o);
    }
    if (lane == 0) {
#pragma unroll
      for (int k = 0; k < 6; ++k) red6[k][wvi] = d[k];
    }
    __syncthreads();
    if (t < 6)
      atomicAdd(&scal[8 + t], red6[t][0] + red6[t][1] + red6[t][2] + red6[t][3]);
  }
}

// ---------------------------------------------------------------------------
// c1b: gates + loss + closed-form norm scalars (sm, sw).
// ---------------------------------------------------------------------------
__global__ __launch_bounds__(256) void c1b_gates(
    const float* __restrict__ gw, const float* __restrict__ gb,
    const float* __restrict__ colk, const float* __restrict__ colv,
    const float* __restrict__ lossp, float* __restrict__ scal,
    float* __restrict__ outp)
{
  __shared__ float red3[3][4];
  __shared__ float redl[4];
  const int t = threadIdx.x, lane = t & 63, wvi = t >> 6;
  float p3[3] = {0.f, 0.f, 0.f};
  for (int j = t; j < 1024; j += 256) {
    const float kv = (j < 512 ? colk[j] : colv[j - 512]) * (1.0f / 32768.0f);
    p3[0] += kv * gw[j];
    p3[1] += kv * gw[1024 + j];
    p3[2] += kv * gw[2048 + j];
  }
  float ls = lossp[t] + lossp[256 + t] + lossp[512 + t] + lossp[768 + t];
#pragma unroll
  for (int o = 32; o; o >>= 1) {
    ls += __shfl_xor(ls, o);
#pragma unroll
    for (int g = 0; g < 3; ++g) p3[g] += __shfl_xor(p3[g], o);
  }
  if (lane == 0) {
    red3[0][wvi] = p3[0]; red3[1][wvi] = p3[1]; red3[2][wvi] = p3[2];
    redl[wvi] = ls;
  }
  __syncthreads();
  if (t == 0) {
    const float s0 = red3[0][0] + red3[0][1] + red3[0][2] + red3[0][3] + gb[0];
    const float s1 = red3[1][0] + red3[1][1] + red3[1][2] + red3[1][3] + gb[1];
    const float s2 = red3[2][0] + red3[2][1] + red3[2][2] + red3[2][3] + gb[2];
    const float alpha = 1.0f / (1.0f + expf(-s0));
    const float eta   = 1.0f / (1.0f + expf(-s1));
    const float theta = 1.0f / (1.0f + expf(-s2));
    const float ct = 0.005f * theta;
    const float SS = scal[8], Sg = scal[9], gg = scal[10];
    const float WW = scal[11], WS = scal[12], Wg = scal[13];
    // ||m_raw||^2 = e^2 SS - 2 e ct Sg + ct^2 gg
    const float nm2 = eta * eta * SS - 2.0f * eta * ct * Sg + ct * ct * gg;
    const float nm = sqrtf(fmaxf(nm2, 0.f));
    const float sm = nm > 5.0f ? 5.0f / (nm + 1e-8f) : 1.0f;
    // <W, m> = sm (e WS - ct Wg);  ||m||^2 = sm^2 nm2
    const float Wmred = sm * (eta * WS - ct * Wg);
    const float oma = 1.0f - alpha;
    const float nw2 = oma * oma * WW + 2.0f * oma * Wmred + sm * sm * nm2;
    const float nw = sqrtf(fmaxf(nw2, 0.f));
    const float sw = nw > 5.0f ? 5.0f / (nw + 1e-8f) : 1.0f;
    scal[3] = alpha; scal[4] = eta; scal[5] = theta;
    scal[6] = sm; scal[7] = sw;
    outp[OUT_LOSS] = (redl[0] + redl[1] + redl[2] + redl[3]) * (1.0f / 16777216.0f);
    outp[OUT_ALPHA]     = alpha;
    outp[OUT_ALPHA + 1] = eta;
    outp[OUT_ALPHA + 2] = theta;
  }
}

// ---------------------------------------------------------------------------
// cF: single pass -> new_momentum, new_weight.
// m = sm*(e S - ct clip(g)); w = sw*((1-a) W + m)
// ---------------------------------------------------------------------------
__global__ __launch_bounds__(256) void cF_final(
    const float* __restrict__ grad, const float* __restrict__ S,
    const float* __restrict__ Wm, const float* __restrict__ scal,
    float* __restrict__ outp)
{
  const float alpha = scal[3], eta = scal[4];
  const float ct = 0.005f * scal[5];
  const float sm = scal[6], sw = scal[7];
  const float oma = 1.0f - alpha;
  const int i = ((blockIdx.x << 8) + threadIdx.x) << 2;
  const float4_t g4 = *reinterpret_cast<const float4_t*>(&grad[i]);
  const float4_t s4 = *reinterpret_cast<const float4_t*>(&S[i]);
  const float4_t w4 = *reinterpret_cast<const float4_t*>(&Wm[i]);
#pragma unroll
  for (int j = 0; j < 4; ++j) {
    float gt = g4[j] * (2.0f / 16777216.0f);
    gt = fminf(1.0f, fmaxf(-1.0f, gt));
    const float m = sm * (eta * s4[j] - ct * gt);
    outp[OUT_MOM + i + j] = m;
    outp[OUT_W + i + j] = sw * (oma * w4[j] + m);
  }
}

// ---------------------------------------------------------------------------
extern "C" void kernel_launch(void* const* d_in, const int* in_sizes, int n_in,
                              void* d_out, int out_size, void* d_ws, size_t ws_size,
                              hipStream_t stream)
{
  const float* Kp = (const float*)d_in[0];
  const float* Vp = (const float*)d_in[1];
  const float* Wp = (const float*)d_in[2];
  const float* GW = (const float*)d_in[3];
  const float* GB = (const float*)d_in[4];
  const float* Sp = (const float*)d_in[5];
  float* outp = (float*)d_out;
  char* ws = (char*)d_ws;

  float* grad            = (float*)(ws + OFF_GRAD);
  float* colk_part       = (float*)(ws + OFF_CKP);
  float* colv_part       = (float*)(ws + OFF_CVP);
  float* loss_part       = (float*)(ws + OFF_LOSSP);
  float* colk            = (float*)(ws + OFF_COLK);
  float* colv            = (float*)(ws + OFF_COLV);
  float* scal            = (float*)(ws + OFF_SCAL);
  unsigned short* w16    = (unsigned short*)(ws + OFF_W16);
  unsigned short* k16    = (unsigned short*)(ws + OFF_K16);
  unsigned short* diff16 = (unsigned short*)(ws + OFF_DIFF);

  k1_convert<<<1056, 256, 0, stream>>>(Kp, Wp, k16, w16, grad, scal);
  k2_gemm<<<1024, 256, 0, stream>>>(k16, w16, Vp, outp, diff16, colv_part, loss_part);
  k3_grad<<<512, 256, 0, stream>>>(diff16, k16, grad, colk_part);
  cR_reduce<<<48, 256, 0, stream>>>(colk_part, colv_part, colk, colv,
                                    grad, Sp, Wp, scal);
  c1b_gates<<<1, 256, 0, stream>>>(GW, GB, colk, colv, loss_part, scal, outp);
  cF_final<<<256, 256, 0, stream>>>(grad, Sp, Wp, scal, outp);
}